// Round 1
// baseline (5952.342 us; speedup 1.0000x reference)
//
#include <hip/hip_runtime.h>

#define NB 16

__device__ __forceinline__ float silu_f(float x){ return x * (1.0f/(1.0f+__expf(-x))); }
__device__ __forceinline__ float sigm_f(float x){ return 1.0f/(1.0f+__expf(-x)); }

// ---------------------------------------------------------------------------
// 1x1 conv + SiLU, NCHW. Each block: 8 output channels (blockIdx.y*8),
// 2048 positions (256 threads x 8 positions strided by 256).
// Weight loads are block-uniform -> scalar loads; value loads coalesced.
// ---------------------------------------------------------------------------
template<int CIN, int CO>
__global__ __launch_bounds__(256) void conv1x1_silu_k(
    const float* __restrict__ in, const float* __restrict__ w,
    const float* __restrict__ bias, float* __restrict__ out,
    int HW, int total)
{
  const int co0 = blockIdx.y * 8;
  const int t = threadIdx.x;
  int ib[8]; int ob[8]; bool val[8];
  #pragma unroll
  for (int j=0;j<8;++j) {
    int pos = blockIdx.x*2048 + j*256 + t;
    val[j] = pos < total;
    int pc = val[j] ? pos : 0;
    int b = pc / HW; int p = pc - b*HW;
    ib[j] = (b*CIN)*HW + p;
    ob[j] = (b*CO + co0)*HW + p;
  }
  float acc[8][8];
  #pragma unroll
  for (int j=0;j<8;++j)
    #pragma unroll
    for (int i=0;i<8;++i) acc[j][i]=0.f;

  #pragma unroll 4
  for (int ci=0; ci<CIN; ++ci) {
    float wv[8];
    #pragma unroll
    for (int i=0;i<8;++i) wv[i] = w[(co0+i)*CIN + ci];
    #pragma unroll
    for (int j=0;j<8;++j) {
      float v = in[ib[j] + ci*HW];
      #pragma unroll
      for (int i=0;i<8;++i) acc[j][i] = fmaf(wv[i], v, acc[j][i]);
    }
  }
  #pragma unroll
  for (int i=0;i<8;++i) {
    float bi = bias[co0+i];
    #pragma unroll
    for (int j=0;j<8;++j) {
      if (val[j]) out[ob[j] + i*HW] = silu_f(acc[j][i] + bi);
    }
  }
}

// ---------------------------------------------------------------------------
// Fused: depthwise 3x3 + SiLU -> 1x1 project (192->96) + residual -> head
// + decode. One block = 32 flat positions (over B*HW).
// IS_CLS: head is 96->80 + sigmoid into out[...,5:85].
// else:   head is 96->4 (reg) and 96->1 (obj), decoded into out[...,0:5].
// ---------------------------------------------------------------------------
template<bool IS_CLS>
__global__ __launch_bounds__(256) void dwproj_head_k(
    const float* __restrict__ ex, const float* __restrict__ xstem,
    const float* __restrict__ wd, const float* __restrict__ bd,
    const float* __restrict__ w2, const float* __restrict__ b2,
    const float* __restrict__ hw_, const float* __restrict__ hb_,
    const float* __restrict__ ow_, const float* __restrict__ ob_,
    float* __restrict__ out, int H, int W, int a0, float sc)
{
  __shared__ float lds1[32*196];   // dw+SiLU result, [p][c] stride 196 (pad vs 192)
  __shared__ float lds2[32*100];   // projected feat,  [p][co] stride 100 (pad vs 96)
  const int t = threadIdx.x;
  const int HW = H*W;
  const int base = blockIdx.x * 32;

  // phase 1: depthwise 3x3 + SiLU
  for (int k=0;k<24;++k) {
    int idx = k*256 + t;
    int p_ = idx & 31, c = idx >> 5;
    int pos = base + p_;
    int b = pos / HW; int rp = pos - b*HW;
    int y = rp / W; int x = rp - y*W;
    const float* exb = ex + (b*192 + c)*HW;
    const float* wdc = wd + c*9;
    float a = bd[c];
    #pragma unroll
    for (int dy=-1; dy<=1; ++dy) {
      int yy = y+dy;
      if ((unsigned)yy < (unsigned)H) {
        #pragma unroll
        for (int dx=-1; dx<=1; ++dx) {
          int xx = x+dx;
          if ((unsigned)xx < (unsigned)W)
            a = fmaf(exb[yy*W+xx], wdc[(dy+1)*3+(dx+1)], a);
        }
      }
    }
    lds1[p_*196 + c] = silu_f(a);
  }
  __syncthreads();

  // phase 2: 1x1 project 192->96 + residual
  for (int k=0;k<12;++k) {
    int idx = k*256 + t;
    int p_ = idx & 31, co = idx >> 5;
    const float4* l4 = (const float4*)(lds1 + p_*196);
    const float4* w4 = (const float4*)(w2 + co*192);
    float a = b2[co];
    #pragma unroll 8
    for (int c4=0;c4<48;++c4) {
      float4 v = l4[c4]; float4 wv = w4[c4];
      a = fmaf(v.x,wv.x, fmaf(v.y,wv.y, fmaf(v.z,wv.z, fmaf(v.w,wv.w, a))));
    }
    int pos = base + p_;
    int b = pos / HW; int rp = pos - b*HW;
    a += xstem[(b*96+co)*HW + rp];
    lds2[p_*100 + co] = a;
  }
  __syncthreads();

  // phase 3: head + decode
  if (IS_CLS) {
    for (int k=0;k<10;++k) {
      int idx = k*256 + t;           // 32*80 = 2560 items
      int c = idx % 80, p_ = idx / 80;
      const float4* f4 = (const float4*)(lds2 + p_*100);
      const float4* w4 = (const float4*)(hw_ + c*96);
      float a = hb_[c];
      #pragma unroll 8
      for (int j=0;j<24;++j) {
        float4 v=f4[j]; float4 wv=w4[j];
        a = fmaf(v.x,wv.x, fmaf(v.y,wv.y, fmaf(v.z,wv.z, fmaf(v.w,wv.w, a))));
      }
      int pos = base + p_;
      int b = pos / HW; int rp = pos - b*HW;
      out[(b*8400 + a0 + rp)*85 + 5 + c] = sigm_f(a);
    }
  } else {
    if (t < 160) {                   // 32*5 items
      int c = t % 5, p_ = t / 5;
      const float4* f4 = (const float4*)(lds2 + p_*100);
      const float* wr = (c<4) ? (hw_ + c*96) : ow_;
      const float4* w4 = (const float4*)wr;
      float a = (c<4) ? hb_[c] : ob_[0];
      #pragma unroll 8
      for (int j=0;j<24;++j) {
        float4 v=f4[j]; float4 wv=w4[j];
        a = fmaf(v.x,wv.x, fmaf(v.y,wv.y, fmaf(v.z,wv.z, fmaf(v.w,wv.w, a))));
      }
      int pos = base + p_;
      int b = pos / HW; int rp = pos - b*HW;
      int y = rp / W; int x = rp - y*W;
      float o;
      if (c==0)      o = (a + (float)x)*sc;
      else if (c==1) o = (a + (float)y)*sc;
      else if (c<4)  o = __expf(a)*sc;
      else           o = sigm_f(a);
      out[(b*8400 + a0 + rp)*85 + c] = o;
    }
  }
}

extern "C" void kernel_launch(void* const* d_in, const int* in_sizes, int n_in,
                              void* d_out, int out_size, void* d_ws, size_t ws_size,
                              hipStream_t stream)
{
  // Inputs may be in setup_inputs() dict order (x0,stem_w0,stem_b0,x1,...) or
  // signature order (x0,x1,x2,stem_w0,stem_b0,...). Indices 9..26 agree in both.
  bool dict = (in_sizes[1] == 96*128);
  const float* X[3]; const float* SW[3]; const float* SB[3];
  if (dict) {
    X[0]=(const float*)d_in[0]; SW[0]=(const float*)d_in[1]; SB[0]=(const float*)d_in[2];
    X[1]=(const float*)d_in[3]; SW[1]=(const float*)d_in[4]; SB[1]=(const float*)d_in[5];
    X[2]=(const float*)d_in[6]; SW[2]=(const float*)d_in[7]; SB[2]=(const float*)d_in[8];
  } else {
    X[0]=(const float*)d_in[0]; X[1]=(const float*)d_in[1]; X[2]=(const float*)d_in[2];
    SW[0]=(const float*)d_in[3]; SB[0]=(const float*)d_in[4];
    SW[1]=(const float*)d_in[5]; SB[1]=(const float*)d_in[6];
    SW[2]=(const float*)d_in[7]; SB[2]=(const float*)d_in[8];
  }
  const float* br_w1[2] = {(const float*)d_in[9],  (const float*)d_in[15]};
  const float* br_b1[2] = {(const float*)d_in[10], (const float*)d_in[16]};
  const float* br_wd[2] = {(const float*)d_in[11], (const float*)d_in[17]};
  const float* br_bd[2] = {(const float*)d_in[12], (const float*)d_in[18]};
  const float* br_w2[2] = {(const float*)d_in[13], (const float*)d_in[19]};
  const float* br_b2[2] = {(const float*)d_in[14], (const float*)d_in[20]};
  const float* clsp_w=(const float*)d_in[21]; const float* clsp_b=(const float*)d_in[22];
  const float* regp_w=(const float*)d_in[23]; const float* regp_b=(const float*)d_in[24];
  const float* objp_w=(const float*)d_in[25]; const float* objp_b=(const float*)d_in[26];

  float* out = (float*)d_out;
  float* ws_stem = (float*)d_ws;            // 96 * 16 * 6400 = 9,830,400 floats
  float* ws_ex   = ws_stem + 96*NB*6400;    // 192 * 16 * 6400 = 19,660,800 floats

  const int Hs[3]  = {80,40,20};
  const int a0s[3] = {0,6400,8000};
  const float scs[3] = {8.f,16.f,32.f};

  for (int k=0;k<3;++k) {
    int H=Hs[k], W=H, HW=H*W, total=NB*HW;
    dim3 blk(256);
    int gx = (total + 2047)/2048;

    // stem: Cin -> 96, SiLU
    if (k==0)
      conv1x1_silu_k<128,96><<<dim3(gx,12),blk,0,stream>>>(X[k],SW[k],SB[k],ws_stem,HW,total);
    else if (k==1)
      conv1x1_silu_k<256,96><<<dim3(gx,12),blk,0,stream>>>(X[k],SW[k],SB[k],ws_stem,HW,total);
    else
      conv1x1_silu_k<512,96><<<dim3(gx,12),blk,0,stream>>>(X[k],SW[k],SB[k],ws_stem,HW,total);

    for (int br=0; br<2; ++br) {   // 0 = cls, 1 = reg
      // expand 96 -> 192, SiLU
      conv1x1_silu_k<96,192><<<dim3(gx,24),blk,0,stream>>>(
          ws_stem, br_w1[br]+k*18432, br_b1[br]+k*192, ws_ex, HW, total);
      if (br==0)
        dwproj_head_k<true><<<dim3(total/32),blk,0,stream>>>(
            ws_ex, ws_stem,
            br_wd[0]+k*1728, br_bd[0]+k*192, br_w2[0]+k*18432, br_b2[0]+k*96,
            clsp_w+k*7680, clsp_b+k*80, objp_w+k*96, objp_b+k,
            out, H, W, a0s[k], scs[k]);
      else
        dwproj_head_k<false><<<dim3(total/32),blk,0,stream>>>(
            ws_ex, ws_stem,
            br_wd[1]+k*1728, br_bd[1]+k*192, br_w2[1]+k*18432, br_b2[1]+k*96,
            regp_w+k*384, regp_b+k*4, objp_w+k*96, objp_b+k,
            out, H, W, a0s[k], scs[k]);
    }
  }
}

// Round 2
// 2108.314 us; speedup vs baseline: 2.8233x; 2.8233x over previous
//
#include <hip/hip_runtime.h>

#define NB 16

typedef unsigned short ushort_t;
typedef unsigned int uint32;
using short8  = __attribute__((ext_vector_type(8))) short;
using floatx4 = __attribute__((ext_vector_type(4))) float;

__device__ __forceinline__ float silu_f(float x){ return x * (1.0f/(1.0f+__expf(-x))); }
__device__ __forceinline__ float sigm_f(float x){ return 1.0f/(1.0f+__expf(-x)); }
__device__ __forceinline__ ushort_t f2bf(float f){
  uint32 u = __float_as_uint(f);
  u += 0x7fffu + ((u>>16)&1u);          // RNE
  return (ushort_t)(u>>16);
}
__device__ __forceinline__ float bf2f(ushort_t h){ return __uint_as_float(((uint32)h)<<16); }

// ---------------------------------------------------------------------------
// Convert 5 fp32 weight blobs to one contiguous bf16 buffer.
// layout: [stemW0 12288][stemW1 24576][stemW2 49152][cls_w1 55296][reg_w1 55296]
// ---------------------------------------------------------------------------
__global__ __launch_bounds__(256) void wconv_k(
    const float* __restrict__ s0, const float* __restrict__ s1,
    const float* __restrict__ s2, const float* __restrict__ s3,
    const float* __restrict__ s4, ushort_t* __restrict__ dst)
{
  int i = blockIdx.x*256 + threadIdx.x;
  if (i >= 196608) return;
  const float* p; int off;
  if      (i < 12288)  { p = s0; off = i; }
  else if (i < 36864)  { p = s1; off = i - 12288; }
  else if (i < 86016)  { p = s2; off = i - 36864; }
  else if (i < 141312) { p = s3; off = i - 86016; }
  else                 { p = s4; off = i - 141312; }
  dst[i] = f2bf(p[off]);
}

// ---------------------------------------------------------------------------
// NCHW fp32 -> [b*HW + p][ci] bf16 (channels-last), LDS 32x256 tile transpose.
// ---------------------------------------------------------------------------
struct TrCfg {
  int b1, b2;          // block-id level boundaries
  int cin[3], hw[3], nbp[3];
  long aoff[3];        // element offsets into xT
};

__global__ __launch_bounds__(256) void transpose_k(
    const float* __restrict__ x0, const float* __restrict__ x1,
    const float* __restrict__ x2, ushort_t* __restrict__ xT, TrCfg cfg)
{
  __shared__ float lds[32*257];
  int bx = blockIdx.x;
  int lvl = (bx < cfg.b1) ? 0 : (bx < cfg.b2 ? 1 : 2);
  int lb  = bx - (lvl==0 ? 0 : (lvl==1 ? cfg.b1 : cfg.b2));
  int CIN = cfg.cin[lvl], HW = cfg.hw[lvl], nbp = cfg.nbp[lvl];
  int nbc = CIN >> 5;
  int per_b = nbc * nbp;
  int b = lb / per_b; int rem = lb - b*per_b;
  int ci0 = (rem / nbp) * 32;
  int p0  = (rem - (rem/nbp)*nbp) * 256;
  const float* xs = (lvl==0 ? x0 : (lvl==1 ? x1 : x2));
  const float* xp = xs + ((long)b*CIN + ci0)*HW;
  int t = threadIdx.x;
  int p = p0 + t;
  #pragma unroll 8
  for (int r=0; r<32; ++r)
    lds[r*257 + t] = (p < HW) ? xp[(long)r*HW + p] : 0.f;
  __syncthreads();
  int subp = t>>3, c4 = (t&7)*4;
  ushort_t* outb = xT + cfg.aoff[lvl] + ci0 + c4;
  for (int g=0; g<8; ++g) {
    int pp = p0 + g*32 + subp;
    if (pp < HW) {
      int col = g*32 + subp;
      ushort4 o;
      o.x = f2bf(lds[(c4+0)*257 + col]);
      o.y = f2bf(lds[(c4+1)*257 + col]);
      o.z = f2bf(lds[(c4+2)*257 + col]);
      o.w = f2bf(lds[(c4+3)*257 + col]);
      *(ushort4*)(outb + (long)(b*HW + pp)*CIN) = o;
    }
  }
}

// ---------------------------------------------------------------------------
// bf16 MFMA GEMM: Out[n][co] = silu( A[n][ci] * W[co][ci]^T + bias[co] ), bf16 out.
// Block: 256 thr = 4 waves; wave covers 64 positions (4 M-tiles of 16) x 96 cos
// (6 N-tiles). No LDS, no barriers: A-frags from channels-last global, B-frags
// from bf16 weights (L1-resident). mfma_f32_16x16x32_bf16 per verified layouts:
//   A lane: m=lane&15, k=quad*8+j ; B lane: n=lane&15, k=quad*8+j
//   D lane: col(n)=lane&15, row(m)=quad*4+reg
// ---------------------------------------------------------------------------
struct GemmCfg {
  long aoff[3];        // element offset into A per level
  long wboff[3];       // element offset into Wb per level
  int  nOff[3];        // flat-n start per level
  int  cin[3];
  int  boff[3];        // bias element offset per level
  int  b1, b2;         // block-id boundaries
  int  costride;
};

__global__ __launch_bounds__(256) void gemm_bf16_k(
    const ushort_t* __restrict__ A, const ushort_t* __restrict__ Wb,
    const float* __restrict__ bp0, const float* __restrict__ bp1,
    const float* __restrict__ bp2, ushort_t* __restrict__ Out, GemmCfg cfg)
{
  int bx = blockIdx.x;
  int lvl = (bx < cfg.b1) ? 0 : (bx < cfg.b2 ? 1 : 2);
  const int CIN = cfg.cin[lvl];
  const int m0  = bx << 8;
  const int co0 = blockIdx.y * 96;
  int t = threadIdx.x, lane = t & 63, wv = t >> 6;
  int mr = lane & 15, quad = lane >> 4;
  const ushort_t* Ap = A + cfg.aoff[lvl]
      + ((long)(m0 - cfg.nOff[lvl] + wv*64 + mr))*CIN + quad*8;
  const ushort_t* Bp = Wb + cfg.wboff[lvl] + ((long)(co0 + mr))*CIN + quad*8;
  const float* bias = (lvl==0 ? bp0 : (lvl==1 ? bp1 : bp2)) + cfg.boff[lvl] + co0;

  floatx4 zero = {0.f, 0.f, 0.f, 0.f};
  floatx4 acc[4][6];
  #pragma unroll
  for (int i=0;i<4;++i)
    #pragma unroll
    for (int j=0;j<6;++j) acc[i][j] = zero;

  const int kc = CIN >> 5;
  for (int k=0; k<kc; ++k) {
    short8 a[4], b[6];
    #pragma unroll
    for (int mt=0; mt<4; ++mt) a[mt] = *(const short8*)(Ap + (long)mt*16*CIN);
    #pragma unroll
    for (int nt=0; nt<6; ++nt) b[nt] = *(const short8*)(Bp + (long)nt*16*CIN);
    #pragma unroll
    for (int mt=0; mt<4; ++mt)
      #pragma unroll
      for (int nt=0; nt<6; ++nt)
        acc[mt][nt] = __builtin_amdgcn_mfma_f32_16x16x32_bf16(a[mt], b[nt], acc[mt][nt], 0, 0, 0);
    Ap += 32; Bp += 32;
  }

  #pragma unroll
  for (int nt=0; nt<6; ++nt) {
    int co = co0 + nt*16 + mr;
    float bv = bias[nt*16 + mr];
    #pragma unroll
    for (int mt=0; mt<4; ++mt) {
      int gm = m0 + wv*64 + mt*16 + quad*4;
      #pragma unroll
      for (int r=0; r<4; ++r) {
        float v = acc[mt][nt][r] + bv;
        Out[(long)(gm + r)*cfg.costride + co] = f2bf(silu_f(v));
      }
    }
  }
}

// ---------------------------------------------------------------------------
// Fused: depthwise 3x3 + SiLU -> 1x1 project (192->96) + residual -> head
// + decode. One block = 32 flat positions. Inputs ex/xs are channels-last bf16.
// ---------------------------------------------------------------------------
template<bool IS_CLS>
__global__ __launch_bounds__(256) void dwproj_head_k(
    const ushort_t* __restrict__ ex, const ushort_t* __restrict__ xs,
    const float* __restrict__ wd, const float* __restrict__ bd,
    const float* __restrict__ w2, const float* __restrict__ b2,
    const float* __restrict__ hw_, const float* __restrict__ hb_,
    const float* __restrict__ ow_, const float* __restrict__ ob_,
    float* __restrict__ out, int H, int W, int a0, float sc, int noff)
{
  __shared__ float lds1[32*196];   // dw+SiLU result, [p][c] pad 196
  __shared__ float lds2[32*100];   // projected feat,  [p][co] pad 100
  const int t = threadIdx.x;
  const int HW = H*W;
  const int base = blockIdx.x * 32;

  // phase 1: depthwise 3x3 + SiLU (c-fast for coalesced channels-last reads)
  for (int idx=t; idx<6144; idx+=256) {
    int p_ = idx/192; int c = idx - p_*192;
    int pos = base + p_;
    int b = pos / HW; int rp = pos - b*HW;
    int y = rp / W; int x = rp - y*W;
    const ushort_t* exb = ex + ((long)(noff + b*HW))*192 + c;
    const float* wdc = wd + c*9;
    float a = bd[c];
    #pragma unroll
    for (int dy=-1; dy<=1; ++dy) {
      int yy = y+dy;
      if ((unsigned)yy < (unsigned)H) {
        #pragma unroll
        for (int dx=-1; dx<=1; ++dx) {
          int xx = x+dx;
          if ((unsigned)xx < (unsigned)W)
            a = fmaf(bf2f(exb[(long)(yy*W+xx)*192]), wdc[(dy+1)*3+(dx+1)], a);
        }
      }
    }
    lds1[p_*196 + c] = silu_f(a);
  }
  __syncthreads();

  // phase 2: 1x1 project 192->96 + residual
  for (int k=0;k<12;++k) {
    int idx = k*256 + t;
    int p_ = idx & 31, co = idx >> 5;
    const float4* l4 = (const float4*)(lds1 + p_*196);
    const float4* w4 = (const float4*)(w2 + co*192);
    float a = b2[co];
    #pragma unroll 8
    for (int c4=0;c4<48;++c4) {
      float4 v = l4[c4]; float4 wv = w4[c4];
      a = fmaf(v.x,wv.x, fmaf(v.y,wv.y, fmaf(v.z,wv.z, fmaf(v.w,wv.w, a))));
    }
    int pos = base + p_;
    a += bf2f(xs[((long)(noff + pos))*96 + co]);
    lds2[p_*100 + co] = a;
  }
  __syncthreads();

  // phase 3: head + decode
  if (IS_CLS) {
    for (int k=0;k<10;++k) {
      int idx = k*256 + t;           // 32*80 = 2560 items
      int c = idx % 80, p_ = idx / 80;
      const float4* f4 = (const float4*)(lds2 + p_*100);
      const float4* w4 = (const float4*)(hw_ + c*96);
      float a = hb_[c];
      #pragma unroll 8
      for (int j=0;j<24;++j) {
        float4 v=f4[j]; float4 wv=w4[j];
        a = fmaf(v.x,wv.x, fmaf(v.y,wv.y, fmaf(v.z,wv.z, fmaf(v.w,wv.w, a))));
      }
      int pos = base + p_;
      int b = pos / HW; int rp = pos - b*HW;
      out[(long)(b*8400 + a0 + rp)*85 + 5 + c] = sigm_f(a);
    }
  } else {
    if (t < 160) {                   // 32*5 items
      int c = t % 5, p_ = t / 5;
      const float4* f4 = (const float4*)(lds2 + p_*100);
      const float* wr = (c<4) ? (hw_ + c*96) : ow_;
      const float4* w4 = (const float4*)wr;
      float a = (c<4) ? hb_[c] : ob_[0];
      #pragma unroll 8
      for (int j=0;j<24;++j) {
        float4 v=f4[j]; float4 wv=w4[j];
        a = fmaf(v.x,wv.x, fmaf(v.y,wv.y, fmaf(v.z,wv.z, fmaf(v.w,wv.w, a))));
      }
      int pos = base + p_;
      int b = pos / HW; int rp = pos - b*HW;
      int y = rp / W; int x = rp - y*W;
      float o;
      if (c==0)      o = (a + (float)x)*sc;
      else if (c==1) o = (a + (float)y)*sc;
      else if (c<4)  o = __expf(a)*sc;
      else           o = sigm_f(a);
      out[(long)(b*8400 + a0 + rp)*85 + c] = o;
    }
  }
}

extern "C" void kernel_launch(void* const* d_in, const int* in_sizes, int n_in,
                              void* d_out, int out_size, void* d_ws, size_t ws_size,
                              hipStream_t stream)
{
  bool dict = (in_sizes[1] == 96*128);
  const float* X[3]; const float* SW[3]; const float* SB[3];
  if (dict) {
    X[0]=(const float*)d_in[0]; SW[0]=(const float*)d_in[1]; SB[0]=(const float*)d_in[2];
    X[1]=(const float*)d_in[3]; SW[1]=(const float*)d_in[4]; SB[1]=(const float*)d_in[5];
    X[2]=(const float*)d_in[6]; SW[2]=(const float*)d_in[7]; SB[2]=(const float*)d_in[8];
  } else {
    X[0]=(const float*)d_in[0]; X[1]=(const float*)d_in[1]; X[2]=(const float*)d_in[2];
    SW[0]=(const float*)d_in[3]; SB[0]=(const float*)d_in[4];
    SW[1]=(const float*)d_in[5]; SB[1]=(const float*)d_in[6];
    SW[2]=(const float*)d_in[7]; SB[2]=(const float*)d_in[8];
  }
  const float* br_w1[2] = {(const float*)d_in[9],  (const float*)d_in[15]};
  const float* br_b1[2] = {(const float*)d_in[10], (const float*)d_in[16]};
  const float* br_wd[2] = {(const float*)d_in[11], (const float*)d_in[17]};
  const float* br_bd[2] = {(const float*)d_in[12], (const float*)d_in[18]};
  const float* br_w2[2] = {(const float*)d_in[13], (const float*)d_in[19]};
  const float* br_b2[2] = {(const float*)d_in[14], (const float*)d_in[20]};
  const float* clsp_w=(const float*)d_in[21]; const float* clsp_b=(const float*)d_in[22];
  const float* regp_w=(const float*)d_in[23]; const float* regp_b=(const float*)d_in[24];
  const float* objp_w=(const float*)d_in[25]; const float* objp_b=(const float*)d_in[26];

  float* out = (float*)d_out;

  // workspace layout (ushort units)
  ushort_t* wbf   = (ushort_t*)d_ws;            // 196,608
  ushort_t* stemO = wbf + 196608;               // 134400*96 = 12,902,400
  ushort_t* reg2  = stemO + 12902400;           // 25,804,800 (xT, then exbuf)

  // 1. weights -> bf16
  wconv_k<<<768,256,0,stream>>>(SW[0],SW[1],SW[2],br_w1[0],br_w1[1],wbf);

  // 2. transpose inputs to channels-last bf16
  TrCfg tc;
  tc.b1 = 1600; tc.b2 = 2496;                   // 1600 + 896 + 512 = 3008
  tc.cin[0]=128; tc.cin[1]=256; tc.cin[2]=512;
  tc.hw[0]=6400; tc.hw[1]=1600; tc.hw[2]=400;
  tc.nbp[0]=25;  tc.nbp[1]=7;   tc.nbp[2]=2;
  tc.aoff[0]=0;  tc.aoff[1]=13107200L; tc.aoff[2]=19660800L;
  transpose_k<<<3008,256,0,stream>>>(X[0],X[1],X[2],reg2,tc);

  // 3. stem GEMM (all levels fused): xT -> stemO [n][96]
  GemmCfg sc_;
  sc_.aoff[0]=0; sc_.aoff[1]=13107200L; sc_.aoff[2]=19660800L;
  sc_.wboff[0]=0; sc_.wboff[1]=12288L; sc_.wboff[2]=36864L;
  sc_.nOff[0]=0; sc_.nOff[1]=102400; sc_.nOff[2]=128000;
  sc_.cin[0]=128; sc_.cin[1]=256; sc_.cin[2]=512;
  sc_.boff[0]=0; sc_.boff[1]=0; sc_.boff[2]=0;
  sc_.b1=400; sc_.b2=500; sc_.costride=96;
  gemm_bf16_k<<<dim3(525,1),256,0,stream>>>(reg2,wbf,SB[0],SB[1],SB[2],stemO,sc_);

  // expand cfg (shared by branches)
  GemmCfg ec;
  ec.aoff[0]=0; ec.aoff[1]=9830400L; ec.aoff[2]=12288000L;
  ec.wboff[0]=0; ec.wboff[1]=18432L; ec.wboff[2]=36864L;
  ec.nOff[0]=0; ec.nOff[1]=102400; ec.nOff[2]=128000;
  ec.cin[0]=96; ec.cin[1]=96; ec.cin[2]=96;
  ec.boff[0]=0; ec.boff[1]=192; ec.boff[2]=384;
  ec.b1=400; ec.b2=500; ec.costride=192;

  const int Hs[3]  = {80,40,20};
  const int a0s[3] = {0,6400,8000};
  const int noffs[3] = {0,102400,128000};
  const float scs[3] = {8.f,16.f,32.f};

  for (int br=0; br<2; ++br) {   // 0 = cls, 1 = reg
    // 4. expand GEMM (all levels, both co-halves): stemO -> reg2 [n][192]
    gemm_bf16_k<<<dim3(525,2),256,0,stream>>>(
        stemO, wbf + (br ? 141312 : 86016),
        br_b1[br], br_b1[br], br_b1[br], reg2, ec);

    // 5. dw + project + head per level
    for (int k=0;k<3;++k) {
      int H=Hs[k], W=H, HW=H*W;
      int grid = NB*HW/32;
      if (br==0)
        dwproj_head_k<true><<<grid,256,0,stream>>>(
            reg2, stemO,
            br_wd[0]+k*1728, br_bd[0]+k*192, br_w2[0]+k*18432, br_b2[0]+k*96,
            clsp_w+k*7680, clsp_b+k*80, objp_w+k*96, objp_b+k,
            out, H, W, a0s[k], scs[k], noffs[k]);
      else
        dwproj_head_k<false><<<grid,256,0,stream>>>(
            reg2, stemO,
            br_wd[1]+k*1728, br_bd[1]+k*192, br_w2[1]+k*18432, br_b2[1]+k*96,
            regp_w+k*384, regp_b+k*4, objp_w+k*96, objp_b+k,
            out, H, W, a0s[k], scs[k], noffs[k]);
    }
  }
}

// Round 3
// 607.871 us; speedup vs baseline: 9.7921x; 3.4684x over previous
//
#include <hip/hip_runtime.h>

#define NB 16

typedef unsigned short ushort_t;
typedef unsigned int uint32;
using short8  = __attribute__((ext_vector_type(8))) short;
using floatx4 = __attribute__((ext_vector_type(4))) float;

__device__ __forceinline__ float silu_f(float x){ return x * (1.0f/(1.0f+__expf(-x))); }
__device__ __forceinline__ float sigm_f(float x){ return 1.0f/(1.0f+__expf(-x)); }
__device__ __forceinline__ ushort_t f2bf(float f){
  uint32 u = __float_as_uint(f);
  u += 0x7fffu + ((u>>16)&1u);          // RNE
  return (ushort_t)(u>>16);
}
__device__ __forceinline__ float bf2f(ushort_t h){ return __uint_as_float(((uint32)h)<<16); }

// ---------------------------------------------------------------------------
// Weight conversion to one bf16 blob. ushort offsets:
//   0        stemW0 12288
//   12288    stemW1 24576
//   36864    stemW2 49152
//   86016    cls_w1 55296
//   141312   reg_w1 55296
//   196608   cls_w2 55296
//   251904   reg_w2 55296
//   307200   clsp_w 23040
//   330240   cls_wdT 5184   ([lvl][j][c] transposed)
//   335424   reg_wdT 5184
//   340608   total
// ---------------------------------------------------------------------------
__global__ __launch_bounds__(256) void wconv_k(
    const float* __restrict__ s0, const float* __restrict__ s1,
    const float* __restrict__ s2, const float* __restrict__ cw1,
    const float* __restrict__ rw1, const float* __restrict__ cw2,
    const float* __restrict__ rw2, const float* __restrict__ chw,
    const float* __restrict__ cwd, const float* __restrict__ rwd,
    ushort_t* __restrict__ dst)
{
  int i = blockIdx.x*256 + threadIdx.x;
  if (i >= 340608) return;
  if (i < 330240) {
    const float* p; int off;
    if      (i < 12288)  { p = s0;  off = i; }
    else if (i < 36864)  { p = s1;  off = i - 12288; }
    else if (i < 86016)  { p = s2;  off = i - 36864; }
    else if (i < 141312) { p = cw1; off = i - 86016; }
    else if (i < 196608) { p = rw1; off = i - 141312; }
    else if (i < 251904) { p = cw2; off = i - 196608; }
    else if (i < 307200) { p = rw2; off = i - 251904; }
    else                 { p = chw; off = i - 307200; }
    dst[i] = f2bf(p[off]);
  } else {
    int rel = i - 330240;
    int br = rel / 5184; int r2 = rel - br*5184;
    int lvl = r2 / 1728; int r3 = r2 - lvl*1728;
    int j = r3 / 192;    int c = r3 - j*192;
    const float* wd = br ? rwd : cwd;
    dst[i] = f2bf(wd[lvl*1728 + c*9 + j]);
  }
}

// ---------------------------------------------------------------------------
// NCHW fp32 -> [n][ci] bf16 channels-last, LDS 32x256 tile transpose.
// ---------------------------------------------------------------------------
struct TrCfg {
  int b1, b2;
  int cin[3], hw[3], nbp[3];
  long aoff[3];
};

__global__ __launch_bounds__(256) void transpose_k(
    const float* __restrict__ x0, const float* __restrict__ x1,
    const float* __restrict__ x2, ushort_t* __restrict__ xT, TrCfg cfg)
{
  __shared__ float lds[32*257];
  int bx = blockIdx.x;
  int lvl = (bx < cfg.b1) ? 0 : (bx < cfg.b2 ? 1 : 2);
  int lb  = bx - (lvl==0 ? 0 : (lvl==1 ? cfg.b1 : cfg.b2));
  int CIN = cfg.cin[lvl], HW = cfg.hw[lvl], nbp = cfg.nbp[lvl];
  int nbc = CIN >> 5;
  int per_b = nbc * nbp;
  int b = lb / per_b; int rem = lb - b*per_b;
  int ci0 = (rem / nbp) * 32;
  int p0  = (rem - (rem/nbp)*nbp) * 256;
  const float* xs = (lvl==0 ? x0 : (lvl==1 ? x1 : x2));
  const float* xp = xs + ((long)b*CIN + ci0)*HW;
  int t = threadIdx.x;
  int p = p0 + t;
  #pragma unroll 8
  for (int r=0; r<32; ++r)
    lds[r*257 + t] = (p < HW) ? xp[(long)r*HW + p] : 0.f;
  __syncthreads();
  int subp = t>>3, c4 = (t&7)*4;
  ushort_t* outb = xT + cfg.aoff[lvl] + ci0 + c4;
  for (int g=0; g<8; ++g) {
    int pp = p0 + g*32 + subp;
    if (pp < HW) {
      int col = g*32 + subp;
      ushort4 o;
      o.x = f2bf(lds[(c4+0)*257 + col]);
      o.y = f2bf(lds[(c4+1)*257 + col]);
      o.z = f2bf(lds[(c4+2)*257 + col]);
      o.w = f2bf(lds[(c4+3)*257 + col]);
      *(ushort4*)(outb + (long)(b*HW + pp)*CIN) = o;
    }
  }
}

// ---------------------------------------------------------------------------
// Stem GEMM (per-level CIN), silu -> bf16 channels-last. (round-2 kernel)
// ---------------------------------------------------------------------------
struct GemmCfg {
  long aoff[3]; long wboff[3]; int nOff[3]; int cin[3]; int boff[3];
  int b1, b2; int costride;
};

__global__ __launch_bounds__(256) void gemm_bf16_k(
    const ushort_t* __restrict__ A, const ushort_t* __restrict__ Wb,
    const float* __restrict__ bp0, const float* __restrict__ bp1,
    const float* __restrict__ bp2, ushort_t* __restrict__ Out, GemmCfg cfg)
{
  int bx = blockIdx.x;
  int lvl = (bx < cfg.b1) ? 0 : (bx < cfg.b2 ? 1 : 2);
  const int CIN = cfg.cin[lvl];
  const int m0  = bx << 8;
  const int co0 = blockIdx.y * 96;
  int t = threadIdx.x, lane = t & 63, wv = t >> 6;
  int mr = lane & 15, quad = lane >> 4;
  const ushort_t* Ap = A + cfg.aoff[lvl]
      + ((long)(m0 - cfg.nOff[lvl] + wv*64 + mr))*CIN + quad*8;
  const ushort_t* Bp = Wb + cfg.wboff[lvl] + ((long)(co0 + mr))*CIN + quad*8;
  const float* bias = (lvl==0 ? bp0 : (lvl==1 ? bp1 : bp2)) + cfg.boff[lvl] + co0;

  floatx4 zero = {0.f, 0.f, 0.f, 0.f};
  floatx4 acc[4][6];
  #pragma unroll
  for (int i=0;i<4;++i)
    #pragma unroll
    for (int j=0;j<6;++j) acc[i][j] = zero;

  const int kc = CIN >> 5;
  for (int k=0; k<kc; ++k) {
    short8 a[4], b[6];
    #pragma unroll
    for (int mt=0; mt<4; ++mt) a[mt] = *(const short8*)(Ap + (long)mt*16*CIN);
    #pragma unroll
    for (int nt=0; nt<6; ++nt) b[nt] = *(const short8*)(Bp + (long)nt*16*CIN);
    #pragma unroll
    for (int mt=0; mt<4; ++mt)
      #pragma unroll
      for (int nt=0; nt<6; ++nt)
        acc[mt][nt] = __builtin_amdgcn_mfma_f32_16x16x32_bf16(a[mt], b[nt], acc[mt][nt], 0, 0, 0);
    Ap += 32; Bp += 32;
  }

  #pragma unroll
  for (int nt=0; nt<6; ++nt) {
    int co = co0 + nt*16 + mr;
    float bv = bias[nt*16 + mr];
    #pragma unroll
    for (int mt=0; mt<4; ++mt) {
      int gm = m0 + wv*64 + mt*16 + quad*4;
      #pragma unroll
      for (int r=0; r<4; ++r) {
        float v = acc[mt][nt][r] + bv;
        Out[(long)(gm + r)*cfg.costride + co] = f2bf(silu_f(v));
      }
    }
  }
}

// ---------------------------------------------------------------------------
// Flat-M GEMM over all levels (M=134400). MODE 0: silu->bf16 (expand).
// MODE 1: +bias+residual->bf16 (project). MODE 2: sigmoid->fp32 out (cls head).
// ---------------------------------------------------------------------------
template<int K, int NT, int MODE>
__global__ __launch_bounds__(256) void gemm2_k(
    const ushort_t* __restrict__ A, const ushort_t* __restrict__ Wb,
    const float* __restrict__ bias, const ushort_t* __restrict__ res,
    float* __restrict__ outf, ushort_t* __restrict__ outb, int costride)
{
  const int m0 = blockIdx.x << 8;
  const int lvl = (m0 < 102400) ? 0 : (m0 < 128000 ? 1 : 2);
  const int co0 = blockIdx.y * (NT*16);
  int t = threadIdx.x, lane = t & 63, wv = t >> 6;
  int mr = lane & 15, quad = lane >> 4;
  const ushort_t* Ap = A + ((long)(m0 + wv*64 + mr))*K + quad*8;
  const ushort_t* Bp = Wb + ((long)(co0 + mr))*K + quad*8;
  const int nbias = (MODE==0) ? 192 : (MODE==1 ? 96 : 80);
  const float* bp = bias + lvl*nbias + co0;

  floatx4 zero = {0.f, 0.f, 0.f, 0.f};
  floatx4 acc[4][NT];
  #pragma unroll
  for (int i=0;i<4;++i)
    #pragma unroll
    for (int j=0;j<NT;++j) acc[i][j] = zero;

  #pragma unroll
  for (int k=0; k<K/32; ++k) {
    short8 a[4], b[NT];
    #pragma unroll
    for (int mt=0; mt<4; ++mt) a[mt] = *(const short8*)(Ap + (long)mt*16*K);
    #pragma unroll
    for (int nt=0; nt<NT; ++nt) b[nt] = *(const short8*)(Bp + (long)nt*16*K);
    #pragma unroll
    for (int mt=0; mt<4; ++mt)
      #pragma unroll
      for (int nt=0; nt<NT; ++nt)
        acc[mt][nt] = __builtin_amdgcn_mfma_f32_16x16x32_bf16(a[mt], b[nt], acc[mt][nt], 0, 0, 0);
    Ap += 32; Bp += 32;
  }

  const int noff = (lvl==0) ? 0 : (lvl==1 ? 102400 : 128000);
  const int HW   = (lvl==0) ? 6400 : (lvl==1 ? 1600 : 400);
  const int a0   = (lvl==0) ? 0 : (lvl==1 ? 6400 : 8000);

  #pragma unroll
  for (int nt=0; nt<NT; ++nt) {
    int co = co0 + nt*16 + mr;
    float bv = bp[nt*16 + mr];
    #pragma unroll
    for (int mt=0; mt<4; ++mt) {
      int gm = m0 + wv*64 + mt*16 + quad*4;
      #pragma unroll
      for (int r=0; r<4; ++r) {
        float v = acc[mt][nt][r] + bv;
        int n = gm + r;
        if (MODE == 0) {
          outb[(long)n*costride + co] = f2bf(silu_f(v));
        } else if (MODE == 1) {
          v += bf2f(res[(long)n*96 + co]);
          outb[(long)n*costride + co] = f2bf(v);
        } else {
          int m = n - noff; int b_ = m / HW; int rp = m - b_*HW;
          outf[((long)(b_*8400 + a0 + rp))*85 + 5 + co] = sigm_f(v);
        }
      }
    }
  }
}

// ---------------------------------------------------------------------------
// Depthwise 3x3 + SiLU, channels-last bf16 -> bf16. Block = 64 positions.
// Thread item = (position, 8-channel group); short8 taps + transposed bf16 w.
// ---------------------------------------------------------------------------
__global__ __launch_bounds__(256) void dw_k(
    const ushort_t* __restrict__ ex, const ushort_t* __restrict__ wdT,
    const float* __restrict__ bd, ushort_t* __restrict__ dwo)
{
  int t = threadIdx.x;
  int base = blockIdx.x * 64;
  int lvl = (base < 102400) ? 0 : (base < 128000 ? 1 : 2);
  int HW  = (lvl==0) ? 6400 : (lvl==1 ? 1600 : 400);
  int W   = (lvl==0) ? 80 : (lvl==1 ? 40 : 20);
  int noff= (lvl==0) ? 0 : (lvl==1 ? 102400 : 128000);
  const ushort_t* wT = wdT + lvl*1728;
  const float* bdl = bd + lvl*192;

  #pragma unroll
  for (int kk=0; kk<6; ++kk) {
    int idx = kk*256 + t;
    int p_ = idx / 24; int g = idx - p_*24; int c = g*8;
    int n = base + p_;
    int m = n - noff;
    int b_ = m / HW; int rp = m - b_*HW;
    int y = rp / W;  int x = rp - y*W;
    float acc[8];
    *(float4*)(acc)   = *(const float4*)(bdl + c);
    *(float4*)(acc+4) = *(const float4*)(bdl + c + 4);
    const ushort_t* exn = ex + (long)n*192 + c;
    #pragma unroll
    for (int dy=-1; dy<=1; ++dy) {
      int yy = y + dy;
      if ((unsigned)yy < (unsigned)W) {
        #pragma unroll
        for (int dx=-1; dx<=1; ++dx) {
          int xx = x + dx;
          if ((unsigned)xx < (unsigned)W) {
            short8 a8 = *(const short8*)(exn + (long)(dy*W + dx)*192);
            short8 w8 = *(const short8*)(wT + ((dy+1)*3 + (dx+1))*192 + c);
            #pragma unroll
            for (int i=0;i<8;++i)
              acc[i] = fmaf(bf2f((ushort_t)a8[i]), bf2f((ushort_t)w8[i]), acc[i]);
          }
        }
      }
    }
    short8 o;
    #pragma unroll
    for (int i=0;i<8;++i) o[i] = (short)f2bf(silu_f(acc[i]));
    *(short8*)(dwo + (long)n*192 + c) = o;
  }
}

// ---------------------------------------------------------------------------
// reg/obj head (N=5) + decode, one thread per position. Weights wave-uniform.
// ---------------------------------------------------------------------------
__global__ __launch_bounds__(256) void regdec_k(
    const ushort_t* __restrict__ proj, const float* __restrict__ rw,
    const float* __restrict__ rb, const float* __restrict__ ow,
    const float* __restrict__ ob, float* __restrict__ out)
{
  int n = blockIdx.x*256 + threadIdx.x;
  int lvl = (n < 102400) ? 0 : (n < 128000 ? 1 : 2);
  int HW  = (lvl==0) ? 6400 : (lvl==1 ? 1600 : 400);
  int W   = (lvl==0) ? 80 : (lvl==1 ? 40 : 20);
  int noff= (lvl==0) ? 0 : (lvl==1 ? 102400 : 128000);
  int a0  = (lvl==0) ? 0 : (lvl==1 ? 6400 : 8000);
  float sc= (lvl==0) ? 8.f : (lvl==1 ? 16.f : 32.f);

  const ushort_t* pr = proj + (long)n*96;
  float f[96];
  #pragma unroll
  for (int j=0;j<12;++j) {
    short8 v = *(const short8*)(pr + j*8);
    #pragma unroll
    for (int i=0;i<8;++i) f[j*8+i] = bf2f((ushort_t)v[i]);
  }
  const float* w0 = rw + lvl*384;
  const float* wo = ow + lvl*96;
  float acc[5];
  #pragma unroll
  for (int c=0;c<4;++c) acc[c] = rb[lvl*4+c];
  acc[4] = ob[lvl];
  #pragma unroll 8
  for (int k=0;k<96;++k) {
    float fv = f[k];
    acc[0] = fmaf(fv, w0[k],      acc[0]);
    acc[1] = fmaf(fv, w0[96+k],   acc[1]);
    acc[2] = fmaf(fv, w0[192+k],  acc[2]);
    acc[3] = fmaf(fv, w0[288+k],  acc[3]);
    acc[4] = fmaf(fv, wo[k],      acc[4]);
  }
  int m = n - noff; int b_ = m / HW; int rp = m - b_*HW;
  int y = rp / W;  int x = rp - y*W;
  long o = ((long)(b_*8400 + a0 + rp))*85;
  out[o+0] = (acc[0] + (float)x)*sc;
  out[o+1] = (acc[1] + (float)y)*sc;
  out[o+2] = __expf(acc[2])*sc;
  out[o+3] = __expf(acc[3])*sc;
  out[o+4] = sigm_f(acc[4]);
}

extern "C" void kernel_launch(void* const* d_in, const int* in_sizes, int n_in,
                              void* d_out, int out_size, void* d_ws, size_t ws_size,
                              hipStream_t stream)
{
  bool dict = (in_sizes[1] == 96*128);
  const float* X[3]; const float* SW[3]; const float* SB[3];
  if (dict) {
    X[0]=(const float*)d_in[0]; SW[0]=(const float*)d_in[1]; SB[0]=(const float*)d_in[2];
    X[1]=(const float*)d_in[3]; SW[1]=(const float*)d_in[4]; SB[1]=(const float*)d_in[5];
    X[2]=(const float*)d_in[6]; SW[2]=(const float*)d_in[7]; SB[2]=(const float*)d_in[8];
  } else {
    X[0]=(const float*)d_in[0]; X[1]=(const float*)d_in[1]; X[2]=(const float*)d_in[2];
    SW[0]=(const float*)d_in[3]; SB[0]=(const float*)d_in[4];
    SW[1]=(const float*)d_in[5]; SB[1]=(const float*)d_in[6];
    SW[2]=(const float*)d_in[7]; SB[2]=(const float*)d_in[8];
  }
  const float* br_w1[2] = {(const float*)d_in[9],  (const float*)d_in[15]};
  const float* br_b1[2] = {(const float*)d_in[10], (const float*)d_in[16]};
  const float* br_wd[2] = {(const float*)d_in[11], (const float*)d_in[17]};
  const float* br_bd[2] = {(const float*)d_in[12], (const float*)d_in[18]};
  const float* br_w2[2] = {(const float*)d_in[13], (const float*)d_in[19]};
  const float* br_b2[2] = {(const float*)d_in[14], (const float*)d_in[20]};
  const float* clsp_w=(const float*)d_in[21]; const float* clsp_b=(const float*)d_in[22];
  const float* regp_w=(const float*)d_in[23]; const float* regp_b=(const float*)d_in[24];
  const float* objp_w=(const float*)d_in[25]; const float* objp_b=(const float*)d_in[26];

  float* out = (float*)d_out;

  // workspace layout (ushort units)
  ushort_t* wbf   = (ushort_t*)d_ws;            // 340,608
  ushort_t* stemO = wbf + 340608;               // 134400*96 = 12,902,400
  ushort_t* bufA  = stemO + 12902400;           // 25,804,800 (xT -> dwbuf)
  ushort_t* bufB  = bufA + 25804800;            // 25,804,800 (exbuf -> projbuf)

  // 1. weights -> bf16 (+ transposed dw weights)
  wconv_k<<<1331,256,0,stream>>>(SW[0],SW[1],SW[2],br_w1[0],br_w1[1],
                                 br_w2[0],br_w2[1],clsp_w,br_wd[0],br_wd[1],wbf);

  // 2. transpose inputs to channels-last bf16 -> bufA
  TrCfg tc;
  tc.b1 = 1600; tc.b2 = 2496;
  tc.cin[0]=128; tc.cin[1]=256; tc.cin[2]=512;
  tc.hw[0]=6400; tc.hw[1]=1600; tc.hw[2]=400;
  tc.nbp[0]=25;  tc.nbp[1]=7;   tc.nbp[2]=2;
  tc.aoff[0]=0;  tc.aoff[1]=13107200L; tc.aoff[2]=19660800L;
  transpose_k<<<3008,256,0,stream>>>(X[0],X[1],X[2],bufA,tc);

  // 3. stem GEMM: bufA -> stemO [n][96]
  GemmCfg sc_;
  sc_.aoff[0]=0; sc_.aoff[1]=13107200L; sc_.aoff[2]=19660800L;
  sc_.wboff[0]=0; sc_.wboff[1]=12288L; sc_.wboff[2]=36864L;
  sc_.nOff[0]=0; sc_.nOff[1]=102400; sc_.nOff[2]=128000;
  sc_.cin[0]=128; sc_.cin[1]=256; sc_.cin[2]=512;
  sc_.boff[0]=0; sc_.boff[1]=0; sc_.boff[2]=0;
  sc_.b1=400; sc_.b2=500; sc_.costride=96;
  gemm_bf16_k<<<dim3(525,1),256,0,stream>>>(bufA,wbf,SB[0],SB[1],SB[2],stemO,sc_);

  for (int br=0; br<2; ++br) {   // 0 = cls, 1 = reg
    // 4. expand GEMM: stemO -> bufB [n][192], silu
    gemm2_k<96,6,0><<<dim3(525,2),256,0,stream>>>(
        stemO, wbf + (br ? 141312 : 86016), br_b1[br], nullptr,
        nullptr, bufB, 192);
    // 5. depthwise 3x3 + silu: bufB -> bufA [n][192]
    dw_k<<<2100,256,0,stream>>>(bufB, wbf + (br ? 335424 : 330240), br_bd[br], bufA);
    // 6. project GEMM + residual: bufA -> bufB [n][96]
    gemm2_k<192,6,1><<<dim3(525,1),256,0,stream>>>(
        bufA, wbf + (br ? 251904 : 196608), br_b2[br], stemO,
        nullptr, bufB, 96);
    // 7. heads
    if (br == 0)
      gemm2_k<96,5,2><<<dim3(525,1),256,0,stream>>>(
          bufB, wbf + 307200, clsp_b, nullptr, out, nullptr, 0);
    else
      regdec_k<<<525,256,0,stream>>>(bufB, regp_w, regp_b, objp_w, objp_b, out);
  }
}

// Round 4
// 553.016 us; speedup vs baseline: 10.7634x; 1.0992x over previous
//
#include <hip/hip_runtime.h>

#define NB 16

typedef unsigned short ushort_t;
typedef unsigned int uint32;
using short8  = __attribute__((ext_vector_type(8))) short;
using floatx4 = __attribute__((ext_vector_type(4))) float;

__device__ __forceinline__ float silu_f(float x){ return x * (1.0f/(1.0f+__expf(-x))); }
__device__ __forceinline__ float sigm_f(float x){ return 1.0f/(1.0f+__expf(-x)); }
__device__ __forceinline__ ushort_t f2bf(float f){
  uint32 u = __float_as_uint(f);
  u += 0x7fffu + ((u>>16)&1u);          // RNE
  return (ushort_t)(u>>16);
}
__device__ __forceinline__ float bf2f(ushort_t h){ return __uint_as_float(((uint32)h)<<16); }
// round-half-up bf16 pair pack: 3 VALU ops per 2 elements
__device__ __forceinline__ uint32 pack_rhu(float f0, float f1){
  uint32 u0 = __float_as_uint(f0) + 0x8000u;
  uint32 u1 = __float_as_uint(f1) + 0x8000u;
  return __builtin_amdgcn_perm(u1, u0, 0x07060302u);  // {u1.hi16, u0.hi16}
}

// ---------------------------------------------------------------------------
// Weight conversion to one bf16 blob. ushort offsets:
//   0        stemW0 12288
//   12288    stemW1 24576
//   36864    stemW2 49152
//   86016    cls_w1 55296
//   141312   reg_w1 55296
//   196608   cls_w2 55296
//   251904   reg_w2 55296
//   307200   clsp_w 23040
//   330240   cls_wdT 5184   ([lvl][j][c] transposed)
//   335424   reg_wdT 5184
//   340608   total
// ---------------------------------------------------------------------------
__global__ __launch_bounds__(256) void wconv_k(
    const float* __restrict__ s0, const float* __restrict__ s1,
    const float* __restrict__ s2, const float* __restrict__ cw1,
    const float* __restrict__ rw1, const float* __restrict__ cw2,
    const float* __restrict__ rw2, const float* __restrict__ chw,
    const float* __restrict__ cwd, const float* __restrict__ rwd,
    ushort_t* __restrict__ dst)
{
  int i = blockIdx.x*256 + threadIdx.x;
  if (i >= 340608) return;
  if (i < 330240) {
    const float* p; int off;
    if      (i < 12288)  { p = s0;  off = i; }
    else if (i < 36864)  { p = s1;  off = i - 12288; }
    else if (i < 86016)  { p = s2;  off = i - 36864; }
    else if (i < 141312) { p = cw1; off = i - 86016; }
    else if (i < 196608) { p = rw1; off = i - 141312; }
    else if (i < 251904) { p = cw2; off = i - 196608; }
    else if (i < 307200) { p = rw2; off = i - 251904; }
    else                 { p = chw; off = i - 307200; }
    dst[i] = f2bf(p[off]);
  } else {
    int rel = i - 330240;
    int br = rel / 5184; int r2 = rel - br*5184;
    int lvl = r2 / 1728; int r3 = r2 - lvl*1728;
    int j = r3 / 192;    int c = r3 - j*192;
    const float* wd = br ? rwd : cwd;
    dst[i] = f2bf(wd[lvl*1728 + c*9 + j]);
  }
}

// ---------------------------------------------------------------------------
// Stem GEMM directly from NCHW fp32 (no transpose). Operand roles swapped:
//   A = weights [co][ci] (K-contig, L1-hot), B = x NCHW = B[k=ci][n=pos].
// Per-lane fp32 loads for B frags, packed to bf16 in-register (RHU).
// Block = 256 pos (4 waves x 64), all 96 co. Out[n][96] = silu bf16.
// ---------------------------------------------------------------------------
__global__ __launch_bounds__(256) void stem_k(
    const float* __restrict__ x0, const float* __restrict__ x1,
    const float* __restrict__ x2, const ushort_t* __restrict__ Wb,
    const float* __restrict__ sb0, const float* __restrict__ sb1,
    const float* __restrict__ sb2, ushort_t* __restrict__ Out)
{
  const int m0 = blockIdx.x << 8;
  const int lvl = (m0 < 102400) ? 0 : (m0 < 128000 ? 1 : 2);
  const int CIN = (lvl==0)?128:(lvl==1?256:512);
  const int HW  = (lvl==0)?6400:(lvl==1?1600:400);
  const int noff= (lvl==0)?0:(lvl==1?102400:128000);
  const float* X = (lvl==0)?x0:(lvl==1?x1:x2);
  const ushort_t* Wl = Wb + ((lvl==0)?0:(lvl==1?12288:36864));
  const float* bias = (lvl==0)?sb0:(lvl==1?sb1:sb2);

  int t=threadIdx.x, lane=t&63, wv=t>>6, mr=lane&15, quad=lane>>4;

  int idx[4];
  #pragma unroll
  for (int nt=0; nt<4; ++nt) {
    int n = m0 + wv*64 + nt*16 + mr;
    int m = n - noff; int b_ = m / HW; int p = m - b_*HW;
    idx[nt] = (b_*CIN + quad*8)*HW + p;
  }
  const ushort_t* Ap = Wl + mr*CIN + quad*8;

  floatx4 zero = {0.f,0.f,0.f,0.f};
  floatx4 acc[6][4];
  #pragma unroll
  for (int i=0;i<6;++i)
    #pragma unroll
    for (int j=0;j<4;++j) acc[i][j] = zero;

  for (int k=0; k<CIN; k+=32) {
    short8 a[6], b[4];
    #pragma unroll
    for (int mt=0; mt<6; ++mt) a[mt] = *(const short8*)(Ap + mt*16*CIN);
    #pragma unroll
    for (int nt=0; nt<4; ++nt) {
      float f[8];
      #pragma unroll
      for (int j=0;j<8;++j) f[j] = X[idx[nt] + j*HW];
      int* bi = (int*)&b[nt];
      #pragma unroll
      for (int j=0;j<4;++j) bi[j] = (int)pack_rhu(f[2*j], f[2*j+1]);
    }
    #pragma unroll
    for (int mt=0; mt<6; ++mt)
      #pragma unroll
      for (int nt=0; nt<4; ++nt)
        acc[mt][nt] = __builtin_amdgcn_mfma_f32_16x16x32_bf16(a[mt], b[nt], acc[mt][nt], 0, 0, 0);
    Ap += 32;
    #pragma unroll
    for (int nt=0; nt<4; ++nt) idx[nt] += 32*HW;
  }

  #pragma unroll
  for (int mt=0; mt<6; ++mt) {
    float4 bv = *(const float4*)(bias + mt*16 + quad*4);
    #pragma unroll
    for (int nt=0; nt<4; ++nt) {
      int pos = m0 + wv*64 + nt*16 + mr;
      ushort4 o;
      o.x = f2bf(silu_f(acc[mt][nt][0] + bv.x));
      o.y = f2bf(silu_f(acc[mt][nt][1] + bv.y));
      o.z = f2bf(silu_f(acc[mt][nt][2] + bv.z));
      o.w = f2bf(silu_f(acc[mt][nt][3] + bv.w));
      *(ushort4*)(Out + (long)pos*96 + mt*16 + quad*4) = o;
    }
  }
}

// ---------------------------------------------------------------------------
// Expand GEMM: [n][96] bf16 -> [n][192] bf16 silu. Flat M over all levels.
// grid (525, 2): y = co half.
// ---------------------------------------------------------------------------
__global__ __launch_bounds__(256) void expand_k(
    const ushort_t* __restrict__ A, const ushort_t* __restrict__ Wb,
    const float* __restrict__ b1, ushort_t* __restrict__ Out)
{
  const int m0 = blockIdx.x << 8;
  const int lvl = (m0 < 102400) ? 0 : (m0 < 128000 ? 1 : 2);
  const int co0 = blockIdx.y * 96;
  int t = threadIdx.x, lane = t & 63, wv = t >> 6;
  int mr = lane & 15, quad = lane >> 4;
  const ushort_t* Ap = A + ((long)(m0 + wv*64 + mr))*96 + quad*8;
  const ushort_t* Bp = Wb + ((long)(co0 + mr))*96 + quad*8;
  const float* bp = b1 + lvl*192 + co0;

  floatx4 zero = {0.f,0.f,0.f,0.f};
  floatx4 acc[4][6];
  #pragma unroll
  for (int i=0;i<4;++i)
    #pragma unroll
    for (int j=0;j<6;++j) acc[i][j] = zero;

  #pragma unroll
  for (int k=0; k<3; ++k) {
    short8 a[4], b[6];
    #pragma unroll
    for (int mt=0; mt<4; ++mt) a[mt] = *(const short8*)(Ap + (long)mt*16*96);
    #pragma unroll
    for (int nt=0; nt<6; ++nt) b[nt] = *(const short8*)(Bp + (long)nt*16*96);
    #pragma unroll
    for (int mt=0; mt<4; ++mt)
      #pragma unroll
      for (int nt=0; nt<6; ++nt)
        acc[mt][nt] = __builtin_amdgcn_mfma_f32_16x16x32_bf16(a[mt], b[nt], acc[mt][nt], 0, 0, 0);
    Ap += 32; Bp += 32;
  }

  #pragma unroll
  for (int nt=0; nt<6; ++nt) {
    int co = co0 + nt*16 + mr;
    float bv = bp[nt*16 + mr];
    #pragma unroll
    for (int mt=0; mt<4; ++mt) {
      int gm = m0 + wv*64 + mt*16 + quad*4;
      #pragma unroll
      for (int r=0; r<4; ++r)
        Out[(long)(gm + r)*192 + co] = f2bf(silu_f(acc[mt][nt][r] + bv));
    }
  }
}

// ---------------------------------------------------------------------------
// Depthwise 3x3 + SiLU, channels-last bf16 -> bf16. Block = 64 positions.
// ---------------------------------------------------------------------------
__global__ __launch_bounds__(256) void dw_k(
    const ushort_t* __restrict__ ex, const ushort_t* __restrict__ wdT,
    const float* __restrict__ bd, ushort_t* __restrict__ dwo)
{
  int t = threadIdx.x;
  int base = blockIdx.x * 64;
  int lvl = (base < 102400) ? 0 : (base < 128000 ? 1 : 2);
  int HW  = (lvl==0) ? 6400 : (lvl==1 ? 1600 : 400);
  int W   = (lvl==0) ? 80 : (lvl==1 ? 40 : 20);
  int noff= (lvl==0) ? 0 : (lvl==1 ? 102400 : 128000);
  const ushort_t* wT = wdT + lvl*1728;
  const float* bdl = bd + lvl*192;

  #pragma unroll
  for (int kk=0; kk<6; ++kk) {
    int idx = kk*256 + t;
    int p_ = idx / 24; int g = idx - p_*24; int c = g*8;
    int n = base + p_;
    int m = n - noff;
    int b_ = m / HW; int rp = m - b_*HW;
    int y = rp / W;  int x = rp - y*W;
    float acc[8];
    *(float4*)(acc)   = *(const float4*)(bdl + c);
    *(float4*)(acc+4) = *(const float4*)(bdl + c + 4);
    const ushort_t* exn = ex + (long)n*192 + c;
    #pragma unroll
    for (int dy=-1; dy<=1; ++dy) {
      int yy = y + dy;
      if ((unsigned)yy < (unsigned)W) {
        #pragma unroll
        for (int dx=-1; dx<=1; ++dx) {
          int xx = x + dx;
          if ((unsigned)xx < (unsigned)W) {
            short8 a8 = *(const short8*)(exn + (long)(dy*W + dx)*192);
            short8 w8 = *(const short8*)(wT + ((dy+1)*3 + (dx+1))*192 + c);
            #pragma unroll
            for (int i=0;i<8;++i)
              acc[i] = fmaf(bf2f((ushort_t)a8[i]), bf2f((ushort_t)w8[i]), acc[i]);
          }
        }
      }
    }
    short8 o;
    #pragma unroll
    for (int i=0;i<8;++i) o[i] = (short)f2bf(silu_f(acc[i]));
    *(short8*)(dwo + (long)n*192 + c) = o;
  }
}

// ---------------------------------------------------------------------------
// Project GEMM (K=192 -> 96) + bias + residual, staged in LDS, then head:
//   IS_CLS: 80-wide MFMA head GEMM + sigmoid -> out[...,5:85]
//   else:   per-thread reg/obj 5-dot + decode -> out[...,0:5]
// Block = 256 pos (4 waves x 64), grid 525.
// ---------------------------------------------------------------------------
template<bool IS_CLS>
__global__ __launch_bounds__(256) void proj_head_k(
    const ushort_t* __restrict__ A, const ushort_t* __restrict__ W2,
    const float* __restrict__ b2, const ushort_t* __restrict__ resid,
    const ushort_t* __restrict__ HWb, const float* __restrict__ hb,
    const float* __restrict__ rw, const float* __restrict__ rb,
    const float* __restrict__ ow, const float* __restrict__ ob,
    float* __restrict__ out)
{
  __shared__ ushort_t lds[256*104];
  const int m0 = blockIdx.x << 8;
  const int lvl = (m0 < 102400) ? 0 : (m0 < 128000 ? 1 : 2);
  const int HW  = (lvl==0) ? 6400 : (lvl==1 ? 1600 : 400);
  const int W   = (lvl==0) ? 80 : (lvl==1 ? 40 : 20);
  const int noff= (lvl==0) ? 0 : (lvl==1 ? 102400 : 128000);
  const int a0  = (lvl==0) ? 0 : (lvl==1 ? 6400 : 8000);

  int t = threadIdx.x, lane = t & 63, wv = t >> 6;
  int mr = lane & 15, quad = lane >> 4;

  {
    const ushort_t* Ap = A + ((long)(m0 + wv*64 + mr))*192 + quad*8;
    const ushort_t* Bp = W2 + lvl*18432 + ((long)mr)*192 + quad*8;
    const float* bp = b2 + lvl*96;

    floatx4 zero = {0.f,0.f,0.f,0.f};
    floatx4 acc[4][6];
    #pragma unroll
    for (int i=0;i<4;++i)
      #pragma unroll
      for (int j=0;j<6;++j) acc[i][j] = zero;

    #pragma unroll
    for (int k=0; k<6; ++k) {
      short8 a[4], b[6];
      #pragma unroll
      for (int mt=0; mt<4; ++mt) a[mt] = *(const short8*)(Ap + (long)mt*16*192);
      #pragma unroll
      for (int nt=0; nt<6; ++nt) b[nt] = *(const short8*)(Bp + (long)nt*16*192);
      #pragma unroll
      for (int mt=0; mt<4; ++mt)
        #pragma unroll
        for (int nt=0; nt<6; ++nt)
          acc[mt][nt] = __builtin_amdgcn_mfma_f32_16x16x32_bf16(a[mt], b[nt], acc[mt][nt], 0, 0, 0);
      Ap += 32; Bp += 32;
    }

    #pragma unroll
    for (int nt=0; nt<6; ++nt) {
      int co = nt*16 + mr;
      float bv = bp[co];
      #pragma unroll
      for (int mt=0; mt<4; ++mt) {
        int row = wv*64 + mt*16 + quad*4;
        int pos = m0 + row;
        #pragma unroll
        for (int r=0; r<4; ++r) {
          float v = acc[mt][nt][r] + bv + bf2f(resid[(long)(pos + r)*96 + co]);
          lds[(row + r)*104 + co] = f2bf(v);
        }
      }
    }
  }
  __syncthreads();

  if (IS_CLS) {
    // head GEMM: A = lds [pos][96], B = clsp [co][96], 5 N-tiles of 16 (co<80)
    const ushort_t* Bp = HWb + lvl*7680 + ((long)mr)*96 + quad*8;
    const float* bp = hb + lvl*80;
    floatx4 zero = {0.f,0.f,0.f,0.f};
    floatx4 acc[4][5];
    #pragma unroll
    for (int i=0;i<4;++i)
      #pragma unroll
      for (int j=0;j<5;++j) acc[i][j] = zero;

    #pragma unroll
    for (int k=0; k<3; ++k) {
      short8 a[4], b[5];
      #pragma unroll
      for (int mt=0; mt<4; ++mt)
        a[mt] = *(const short8*)(lds + (wv*64 + mt*16 + mr)*104 + k*32 + quad*8);
      #pragma unroll
      for (int nt=0; nt<5; ++nt)
        b[nt] = *(const short8*)(Bp + (long)nt*16*96 + k*32);
      #pragma unroll
      for (int mt=0; mt<4; ++mt)
        #pragma unroll
        for (int nt=0; nt<5; ++nt)
          acc[mt][nt] = __builtin_amdgcn_mfma_f32_16x16x32_bf16(a[mt], b[nt], acc[mt][nt], 0, 0, 0);
    }

    #pragma unroll
    for (int nt=0; nt<5; ++nt) {
      int co = nt*16 + mr;
      float bv = bp[co];
      #pragma unroll
      for (int mt=0; mt<4; ++mt) {
        int pos = m0 + wv*64 + mt*16 + quad*4;
        #pragma unroll
        for (int r=0; r<4; ++r) {
          int m = pos + r - noff; int b_ = m / HW; int rp = m - b_*HW;
          out[((long)(b_*8400 + a0 + rp))*85 + 5 + co] = sigm_f(acc[mt][nt][r] + bv);
        }
      }
    }
  } else {
    // reg/obj head: thread t -> pos m0+t, read its 96-ch row from LDS
    int pos = m0 + t;
    float f[96];
    #pragma unroll
    for (int j=0;j<12;++j) {
      short8 v = *(const short8*)(lds + t*104 + j*8);
      #pragma unroll
      for (int i=0;i<8;++i) f[j*8+i] = bf2f((ushort_t)v[i]);
    }
    const float* w0 = rw + lvl*384;
    const float* wo = ow + lvl*96;
    float acc[5];
    #pragma unroll
    for (int c=0;c<4;++c) acc[c] = rb[lvl*4+c];
    acc[4] = ob[lvl];
    #pragma unroll 8
    for (int k=0;k<96;++k) {
      float fv = f[k];
      acc[0] = fmaf(fv, w0[k],      acc[0]);
      acc[1] = fmaf(fv, w0[96+k],   acc[1]);
      acc[2] = fmaf(fv, w0[192+k],  acc[2]);
      acc[3] = fmaf(fv, w0[288+k],  acc[3]);
      acc[4] = fmaf(fv, wo[k],      acc[4]);
    }
    float sc = (lvl==0) ? 8.f : (lvl==1 ? 16.f : 32.f);
    int m = pos - noff; int b_ = m / HW; int rp = m - b_*HW;
    int y = rp / W;  int x = rp - y*W;
    long o = ((long)(b_*8400 + a0 + rp))*85;
    out[o+0] = (acc[0] + (float)x)*sc;
    out[o+1] = (acc[1] + (float)y)*sc;
    out[o+2] = __expf(acc[2])*sc;
    out[o+3] = __expf(acc[3])*sc;
    out[o+4] = sigm_f(acc[4]);
  }
}

extern "C" void kernel_launch(void* const* d_in, const int* in_sizes, int n_in,
                              void* d_out, int out_size, void* d_ws, size_t ws_size,
                              hipStream_t stream)
{
  bool dict = (in_sizes[1] == 96*128);
  const float* X[3]; const float* SW[3]; const float* SB[3];
  if (dict) {
    X[0]=(const float*)d_in[0]; SW[0]=(const float*)d_in[1]; SB[0]=(const float*)d_in[2];
    X[1]=(const float*)d_in[3]; SW[1]=(const float*)d_in[4]; SB[1]=(const float*)d_in[5];
    X[2]=(const float*)d_in[6]; SW[2]=(const float*)d_in[7]; SB[2]=(const float*)d_in[8];
  } else {
    X[0]=(const float*)d_in[0]; X[1]=(const float*)d_in[1]; X[2]=(const float*)d_in[2];
    SW[0]=(const float*)d_in[3]; SB[0]=(const float*)d_in[4];
    SW[1]=(const float*)d_in[5]; SB[1]=(const float*)d_in[6];
    SW[2]=(const float*)d_in[7]; SB[2]=(const float*)d_in[8];
  }
  const float* br_w1[2] = {(const float*)d_in[9],  (const float*)d_in[15]};
  const float* br_b1[2] = {(const float*)d_in[10], (const float*)d_in[16]};
  const float* br_wd[2] = {(const float*)d_in[11], (const float*)d_in[17]};
  const float* br_bd[2] = {(const float*)d_in[12], (const float*)d_in[18]};
  const float* br_w2[2] = {(const float*)d_in[13], (const float*)d_in[19]};
  const float* br_b2[2] = {(const float*)d_in[14], (const float*)d_in[20]};
  const float* clsp_w=(const float*)d_in[21]; const float* clsp_b=(const float*)d_in[22];
  const float* regp_w=(const float*)d_in[23]; const float* regp_b=(const float*)d_in[24];
  const float* objp_w=(const float*)d_in[25]; const float* objp_b=(const float*)d_in[26];

  float* out = (float*)d_out;

  // workspace layout (ushort units), total ~130 MB
  ushort_t* wbf   = (ushort_t*)d_ws;            // 340,608
  ushort_t* stemO = wbf + 340608;               // 134400*96 = 12,902,400
  ushort_t* bufA  = stemO + 12902400;           // 134400*192 = 25,804,800 (expand out)
  ushort_t* bufB  = bufA + 25804800;            // 25,804,800 (dw out)

  // 1. weights -> bf16 blob
  wconv_k<<<1331,256,0,stream>>>(SW[0],SW[1],SW[2],br_w1[0],br_w1[1],
                                 br_w2[0],br_w2[1],clsp_w,br_wd[0],br_wd[1],wbf);

  // 2. stem GEMM straight from NCHW fp32
  stem_k<<<525,256,0,stream>>>(X[0],X[1],X[2],wbf,SB[0],SB[1],SB[2],stemO);

  for (int br=0; br<2; ++br) {   // 0 = cls, 1 = reg
    // 3. expand GEMM: stemO -> bufA [n][192], silu
    expand_k<<<dim3(525,2),256,0,stream>>>(
        stemO, wbf + (br ? 141312 : 86016), br_b1[br], bufA);
    // 4. depthwise 3x3 + silu: bufA -> bufB
    dw_k<<<2100,256,0,stream>>>(bufA, wbf + (br ? 335424 : 330240), br_bd[br], bufB);
    // 5. project + residual + head, fused
    if (br == 0)
      proj_head_k<true><<<525,256,0,stream>>>(
          bufB, wbf + 196608, br_b2[0], stemO,
          wbf + 307200, clsp_b, nullptr, nullptr, nullptr, nullptr, out);
    else
      proj_head_k<false><<<525,256,0,stream>>>(
          bufB, wbf + 251904, br_b2[1], stemO,
          nullptr, nullptr, regp_w, regp_b, objp_w, objp_b, out);
  }
}